// Round 4
// baseline (328.554 us; speedup 1.0000x reference)
//
#include <hip/hip_runtime.h>
#include <math.h>

#define L_SEQ   2048
#define DLLM    768
#define E_DIM   64
#define NSLICE  16
#define EPSV    1e-5f

typedef _Float16 f16;
typedef _Float16 f16x8 __attribute__((ext_vector_type(8)));
typedef _Float16 f16x4 __attribute__((ext_vector_type(4)));
typedef float    f32x4 __attribute__((ext_vector_type(4)));

// ---------------------------------------------------------------------------
// prep: Wt16[192][768] = [Wq^T * 0.125 | Wk^T | Wv^T] fp16 ; bias[192] fp32
// ---------------------------------------------------------------------------
__global__ __launch_bounds__(256)
void prep_kernel(const float* __restrict__ Wq, const float* __restrict__ bq,
                 const float* __restrict__ Wk, const float* __restrict__ bk,
                 const float* __restrict__ Wv, const float* __restrict__ bv,
                 f16* __restrict__ Wt, float* __restrict__ bias)
{
    int b = blockIdx.x;
    if (b < 192) {
        int sel = b >> 6, c = b & 63;
        const float* W = (sel == 0) ? Wq : (sel == 1) ? Wk : Wv;
        float s = (sel == 0) ? 0.125f : 1.0f;
        for (int kd = threadIdx.x; kd < DLLM; kd += 256)
            Wt[b * DLLM + kd] = (f16)(W[kd * 64 + c] * s);
    } else {
        int t = threadIdx.x;
        if (t < 192) {
            int sel = t >> 6, c = t & 63;
            const float* bb = (sel == 0) ? bq : (sel == 1) ? bk : bv;
            bias[t] = bb[c] * ((sel == 0) ? 0.125f : 1.0f);
        }
    }
}

// ---------------------------------------------------------------------------
// proj: pure-streaming MFMA GEMM, no LDS, no barriers.
// wave tile: 32 rows x 96 cols; 2048 waves (512 blocks x 4).
// A (info fp32) prefetched one k-step ahead; B (Wt fp16) from L2 in-iter.
// q,k stored [row][64]; V stored TRANSPOSED per slice: vT[slice][64][2048].
// ---------------------------------------------------------------------------
__global__ __launch_bounds__(256)
void proj_mfma(const float* __restrict__ info, const f16* __restrict__ Wt,
               const float* __restrict__ bias,
               f16* __restrict__ q16, f16* __restrict__ k16, f16* __restrict__ vT)
{
    const int tid = threadIdx.x;
    const int l   = tid & 63;
    const int wid = tid >> 6;
    const int l15 = l & 15, lg = l >> 4;
    const int w   = blockIdx.x * 4 + wid;   // 0..2047
    const int rt  = w >> 1;                 // 0..1023
    const int ch  = w & 1;
    const int r0  = rt * 32;
    const int n0  = ch * 96;

    f32x4 acc[2][6];
    #pragma unroll
    for (int mi = 0; mi < 2; ++mi)
        #pragma unroll
        for (int ni = 0; ni < 6; ++ni) acc[mi][ni] = (f32x4)(0.0f);

    // A-lane base pointers: row r0 + mi*16 + l15, k offset kf*32 + lg*8
    const float* abase[2];
    #pragma unroll
    for (int mi = 0; mi < 2; ++mi)
        abase[mi] = info + (size_t)(r0 + mi * 16 + l15) * DLLM + lg * 8;
    const f16* bbase[6];
    #pragma unroll
    for (int ni = 0; ni < 6; ++ni)
        bbase[ni] = Wt + (size_t)(n0 + ni * 16 + l15) * DLLM + lg * 8;

    float4 alo[2][2][2], ahi[2][2][2];   // [buf][mi][kf]

    // preload k-step 0
    #pragma unroll
    for (int mi = 0; mi < 2; ++mi)
        #pragma unroll
        for (int kf = 0; kf < 2; ++kf) {
            alo[0][mi][kf] = *reinterpret_cast<const float4*>(abase[mi] + kf * 32);
            ahi[0][mi][kf] = *reinterpret_cast<const float4*>(abase[mi] + kf * 32 + 4);
        }

    #pragma unroll
    for (int ks = 0; ks < 12; ++ks) {
        const int cur = ks & 1, nxt = cur ^ 1;
        const int k0 = ks * 64;
        // prefetch next A
        if (ks < 11) {
            #pragma unroll
            for (int mi = 0; mi < 2; ++mi)
                #pragma unroll
                for (int kf = 0; kf < 2; ++kf) {
                    alo[nxt][mi][kf] = *reinterpret_cast<const float4*>(
                        abase[mi] + k0 + 64 + kf * 32);
                    ahi[nxt][mi][kf] = *reinterpret_cast<const float4*>(
                        abase[mi] + k0 + 64 + kf * 32 + 4);
                }
        }
        // B frags from L2
        f16x8 bf[6][2];
        #pragma unroll
        for (int ni = 0; ni < 6; ++ni)
            #pragma unroll
            for (int kf = 0; kf < 2; ++kf)
                bf[ni][kf] = *reinterpret_cast<const f16x8*>(bbase[ni] + k0 + kf * 32);
        // cvt A
        f16x8 af[2][2];
        #pragma unroll
        for (int mi = 0; mi < 2; ++mi)
            #pragma unroll
            for (int kf = 0; kf < 2; ++kf) {
                float4 lo = alo[cur][mi][kf], hi = ahi[cur][mi][kf];
                f16x8 h;
                h[0] = (f16)lo.x; h[1] = (f16)lo.y; h[2] = (f16)lo.z; h[3] = (f16)lo.w;
                h[4] = (f16)hi.x; h[5] = (f16)hi.y; h[6] = (f16)hi.z; h[7] = (f16)hi.w;
                af[mi][kf] = h;
            }
        #pragma unroll
        for (int kf = 0; kf < 2; ++kf)
            #pragma unroll
            for (int mi = 0; mi < 2; ++mi)
                #pragma unroll
                for (int ni = 0; ni < 6; ++ni)
                    acc[mi][ni] = __builtin_amdgcn_mfma_f32_16x16x32_f16(
                        af[mi][kf], bf[ni][kf], acc[mi][ni], 0, 0, 0);
    }

    // epilogue
    #pragma unroll
    for (int ni = 0; ni < 6; ++ni) {
        const int nb  = n0 + ni * 16;        // block base (uniform)
        const int n   = nb + l15;
        const int sel = nb >> 6;             // 0=q 1=k 2=v (uniform per ni)
        const int cc  = (nb & 63) + l15;
        const float bcol = bias[n];
        if (sel < 2) {
            f16* dst = (sel == 0) ? q16 : k16;
            #pragma unroll
            for (int mi = 0; mi < 2; ++mi)
                #pragma unroll
                for (int rr = 0; rr < 4; ++rr) {
                    int r = r0 + mi * 16 + lg * 4 + rr;
                    dst[(size_t)r * E_DIM + cc] = (f16)(acc[mi][ni][rr] + bcol);
                }
        } else {
            // transposed V store: vT[slice][e=cc][l], rows consecutive -> f16x4
            #pragma unroll
            for (int mi = 0; mi < 2; ++mi) {
                int rb    = r0 + mi * 16 + lg * 4;
                int slice = rb >> 11;
                int lloc  = rb & 2047;
                f16x4 v4;
                #pragma unroll
                for (int rr = 0; rr < 4; ++rr) v4[rr] = (f16)(acc[mi][ni][rr] + bcol);
                *reinterpret_cast<f16x4*>(
                    vT + (size_t)slice * E_DIM * L_SEQ + (size_t)cc * L_SEQ + lloc) = v4;
            }
        }
    }
}

// ---------------------------------------------------------------------------
// attn: barrier-free flash attention, swapped QK^T + O^T PV.
// 4 waves x 16 q-rows; K, V^T fragments straight from global (L2-resident).
// Lane (l15,lg) owns q-row l15 for softmax; P bounced via wave-private LDS.
// ---------------------------------------------------------------------------
#define PSTRD 72   // f16 units; 144 B rows (16B aligned)

__global__ __launch_bounds__(256)
void attn_mfma(const f16* __restrict__ q16, const f16* __restrict__ k16,
               const f16* __restrict__ vT, float* __restrict__ att)
{
    __shared__ f16 Pl[4 * 16 * PSTRD];   // 9216 B, wave-private slabs

    const int tid = threadIdx.x;
    const int l   = tid & 63;
    const int wid = tid >> 6;
    const int l15 = l & 15, lg = l >> 4;
    const int slice = blockIdx.y;
    const int q0 = blockIdx.x * 64 + wid * 16;
    const f16* qp = q16 + (size_t)slice * L_SEQ * E_DIM;
    const f16* kp = k16 + (size_t)slice * L_SEQ * E_DIM;
    const f16* vp = vT  + (size_t)slice * E_DIM * L_SEQ;
    f16* P = &Pl[wid * 16 * PSTRD];

    // Q fragment (B-operand): lane supplies Q[q0+l15][kf*32+lg*8+j]
    f16x8 qf[2];
    #pragma unroll
    for (int kf = 0; kf < 2; ++kf)
        qf[kf] = *reinterpret_cast<const f16x8*>(
            qp + (size_t)(q0 + l15) * E_DIM + kf * 32 + lg * 8);

    f32x4 oacc[4];   // O^T[e-block ei][e=lg*4+r][q=l15]
    #pragma unroll
    for (int ei = 0; ei < 4; ++ei) oacc[ei] = (f32x4)(0.0f);
    float M = -1e30f, Lr = 0.f;

    for (int kv0 = 0; kv0 < L_SEQ; kv0 += 64) {
        // S^T = K Q : lane holds S[q=l15][kv = kv0 + ni*16 + lg*4 + r]
        f32x4 s[4];
        #pragma unroll
        for (int ni = 0; ni < 4; ++ni) s[ni] = (f32x4)(0.0f);
        #pragma unroll
        for (int kf = 0; kf < 2; ++kf)
            #pragma unroll
            for (int ni = 0; ni < 4; ++ni) {
                f16x8 kb = *reinterpret_cast<const f16x8*>(
                    kp + (size_t)(kv0 + ni * 16 + l15) * E_DIM + kf * 32 + lg * 8);
                s[ni] = __builtin_amdgcn_mfma_f32_16x16x32_f16(kb, qf[kf], s[ni], 0, 0, 0);
            }

        // online softmax, q-row fully lane-local (plus 2 cross-lane reduces)
        float mx = -1e30f;
        #pragma unroll
        for (int ni = 0; ni < 4; ++ni)
            #pragma unroll
            for (int r = 0; r < 4; ++r) mx = fmaxf(mx, s[ni][r]);
        mx = fmaxf(mx, __shfl_xor(mx, 16));
        mx = fmaxf(mx, __shfl_xor(mx, 32));
        float Mn  = fmaxf(M, mx);
        float fsc = __expf(M - Mn);
        M = Mn;
        float psum = 0.f;
        #pragma unroll
        for (int ni = 0; ni < 4; ++ni) {
            f16x4 p4;
            #pragma unroll
            for (int r = 0; r < 4; ++r) {
                float p = __expf(s[ni][r] - Mn);
                psum += p;
                p4[r] = (f16)p;
            }
            *reinterpret_cast<f16x4*>(&P[l15 * PSTRD + ni * 16 + lg * 4]) = p4;
        }
        Lr = Lr * fsc + psum;
        #pragma unroll
        for (int ei = 0; ei < 4; ++ei) {
            oacc[ei][0] *= fsc; oacc[ei][1] *= fsc;
            oacc[ei][2] *= fsc; oacc[ei][3] *= fsc;
        }

        // O^T += V^T P^T : A = V^T frag (rows e), B = P frag (cols q)
        #pragma unroll
        for (int kf = 0; kf < 2; ++kf) {
            f16x8 pa = *reinterpret_cast<const f16x8*>(
                &P[l15 * PSTRD + kf * 32 + lg * 8]);
            #pragma unroll
            for (int ei = 0; ei < 4; ++ei) {
                f16x8 vb = *reinterpret_cast<const f16x8*>(
                    vp + (size_t)(ei * 16 + l15) * L_SEQ + kv0 + kf * 32 + lg * 8);
                oacc[ei] = __builtin_amdgcn_mfma_f32_16x16x32_f16(vb, pa, oacc[ei], 0, 0, 0);
            }
        }
    }

    // finalize: row sum across the 4 lg copies, divide, store O (fp32)
    float lt = Lr;
    lt += __shfl_xor(lt, 16);
    lt += __shfl_xor(lt, 32);
    float inv = 1.f / lt;
    size_t row = (size_t)slice * L_SEQ + q0 + l15;
    #pragma unroll
    for (int ei = 0; ei < 4; ++ei) {
        float4 o;
        o.x = oacc[ei][0] * inv; o.y = oacc[ei][1] * inv;
        o.z = oacc[ei][2] * inv; o.w = oacc[ei][3] * inv;
        *reinterpret_cast<float4*>(att + row * E_DIM + ei * 16 + lg * 4) = o;
    }
}

// ---------------------------------------------------------------------------
// InstanceNorm: per-block partial sums (no atomics, no init), then apply
// ---------------------------------------------------------------------------
__global__ __launch_bounds__(256)
void stats_kernel(const float* __restrict__ att, float* __restrict__ parts)
{
    const int slice = blockIdx.x >> 4;
    const int part  = blockIdx.x & 15;
    const int tid = threadIdx.x;
    const size_t base = (size_t)slice * L_SEQ * E_DIM + (size_t)part * 8192;
    float s = 0.f, sq = 0.f;
    #pragma unroll
    for (int it = 0; it < 8; ++it) {
        float4 v = *reinterpret_cast<const float4*>(att + base + (size_t)(it * 256 + tid) * 4);
        s  += v.x + v.y + v.z + v.w;
        sq += v.x * v.x + v.y * v.y + v.z * v.z + v.w * v.w;
    }
    for (int m = 1; m < 64; m <<= 1) {
        s  += __shfl_xor(s,  m);
        sq += __shfl_xor(sq, m);
    }
    __shared__ float red[8];
    const int wid = tid >> 6;
    if ((tid & 63) == 0) { red[wid * 2] = s; red[wid * 2 + 1] = sq; }
    __syncthreads();
    if (tid == 0) {
        parts[slice * 32 + part * 2]     = red[0] + red[2] + red[4] + red[6];
        parts[slice * 32 + part * 2 + 1] = red[1] + red[3] + red[5] + red[7];
    }
}

__global__ __launch_bounds__(256)
void apply_kernel(float* __restrict__ att, const float* __restrict__ parts)
{
    const int i4 = blockIdx.x * 256 + threadIdx.x;
    const size_t fl = (size_t)i4 * 4;
    const int slice = (int)(fl >> 17);
    float S = 0.f, SQ = 0.f;
    #pragma unroll
    for (int p = 0; p < 16; ++p) {
        S  += parts[slice * 32 + p * 2];
        SQ += parts[slice * 32 + p * 2 + 1];
    }
    const float N = (float)(L_SEQ * E_DIM);
    float mean = S / N;
    float var  = SQ / N - mean * mean;
    float inv  = rsqrtf(var + EPSV);
    float4 v = *reinterpret_cast<const float4*>(att + fl);
    float4 o;
    o.x = (v.x - mean) * inv;
    o.y = (v.y - mean) * inv;
    o.z = (v.z - mean) * inv;
    o.w = (v.w - mean) * inv;
    *reinterpret_cast<float4*>(att + fl) = o;
}

// ---------------------------------------------------------------------------
extern "C" void kernel_launch(void* const* d_in, const int* in_sizes, int n_in,
                              void* d_out, int out_size, void* d_ws, size_t ws_size,
                              hipStream_t stream)
{
    const float* info = (const float*)d_in[0];
    const float* Wq   = (const float*)d_in[1];
    const float* bq   = (const float*)d_in[2];
    const float* Wk   = (const float*)d_in[3];
    const float* bk   = (const float*)d_in[4];
    const float* Wv   = (const float*)d_in[5];
    const float* bv   = (const float*)d_in[6];

    // Workspace footprint: 13 MB (known-safe from round 3)
    char* ws = (char*)d_ws;
    f16*   Wt    = (f16*)(ws);                       // 294912 B
    float* bias  = (float*)(ws + 294912);            // 768 B
    float* parts = (float*)(ws + 295936);            // 2048 B
    f16*   q16   = (f16*)(ws + 1048576);             // 4 MB
    f16*   k16   = (f16*)(ws + 5242880);             // 4 MB
    f16*   vT    = (f16*)(ws + 9437184);             // 4 MB (end 13 MB)
    float* att   = (float*)d_out;

    prep_kernel<<<193, 256, 0, stream>>>(Wq, bq, Wk, bk, Wv, bv, Wt, bias);
    proj_mfma<<<512, 256, 0, stream>>>(info, Wt, bias, q16, k16, vT);
    attn_mfma<<<dim3(L_SEQ / 64, NSLICE), 256, 0, stream>>>(q16, k16, vT, att);
    stats_kernel<<<256, 256, 0, stream>>>(att, parts);
    apply_kernel<<<2048, 256, 0, stream>>>(att, parts);
}